// Round 14
// baseline (246.518 us; speedup 1.0000x reference)
//
#include <hip/hip_runtime.h>
#include <hip/hip_bf16.h>

#define T_SEQ 2048
#define HID   1024
#define NH    16
#define HD    64
#define NB    2

typedef __bf16 bf16_t;
typedef bf16_t bf16x8 __attribute__((ext_vector_type(8)));
typedef bf16_t bf16x4 __attribute__((ext_vector_type(4)));
typedef float  f32x4  __attribute__((ext_vector_type(4)));

static __device__ __forceinline__ f32x4 mfma16(bf16x8 a, bf16x8 b, f32x4 c) {
    return __builtin_amdgcn_mfma_f32_16x16x32_bf16(a, b, c, 0, 0, 0);
}

// Async global->LDS, 16B per lane (LDS dest wave-uniform base + lane*16;
// per-lane source pre-swizzled so read-side XOR addressing is unchanged).
static __device__ __forceinline__ void gll16(const bf16_t* g, bf16_t* l) {
    __builtin_amdgcn_global_load_lds(
        (const __attribute__((address_space(1))) void*)g,
        (__attribute__((address_space(3))) void*)l, 16, 0, 0);
}

// One-pass f32 -> bf16 conversion of x, pos, and all 5 weights.
__global__ __launch_bounds__(256) void cvt_all(
    const float* __restrict__ x, const float* __restrict__ pos,
    const float* __restrict__ wq, const float* __restrict__ wk,
    const float* __restrict__ wv, const float* __restrict__ wo,
    const float* __restrict__ wrel,
    bf16_t* __restrict__ xb, bf16_t* __restrict__ pb,
    bf16_t* __restrict__ wqb, bf16_t* __restrict__ wkb,
    bf16_t* __restrict__ wvb, bf16_t* __restrict__ wob,
    bf16_t* __restrict__ wrelb)
{
    int blk = blockIdx.x;
    const float* in; bf16_t* out;
    if (blk < 2048)      { in = x;   out = xb; }
    else if (blk < 3072) { in = pos; out = pb; blk -= 2048; }
    else {
        const int wi = (blk - 3072) >> 9; blk = (blk - 3072) & 511;
        switch (wi) {
            case 0:  in = wq;   out = wqb;   break;
            case 1:  in = wk;   out = wkb;   break;
            case 2:  in = wv;   out = wvb;   break;
            case 3:  in = wo;   out = wob;   break;
            default: in = wrel; out = wrelb; break;
        }
    }
    const int i = blk * 256 + threadIdx.x;
    const float4* p = (const float4*)(in + (size_t)i * 8);
    float4 a0 = p[0], a1 = p[1];
    bf16x8 v;
    v[0]=(bf16_t)a0.x; v[1]=(bf16_t)a0.y; v[2]=(bf16_t)a0.z; v[3]=(bf16_t)a0.w;
    v[4]=(bf16_t)a1.x; v[5]=(bf16_t)a1.y; v[6]=(bf16_t)a1.z; v[7]=(bf16_t)a1.w;
    *(bf16x8*)(out + (size_t)i * 8) = v;
}

// Shared 128x128-tile GEMM core (unchanged from round 12 — measured good).
static __device__ __forceinline__ void gemm_core(
    bf16_t* Al, bf16_t* Bl,
    const bf16_t* __restrict__ A, const bf16_t* __restrict__ W,
    void* __restrict__ outv, int row0, int col0, int omode)
{
    const int tid = threadIdx.x;
    const int w = tid >> 6, lane = tid & 63;
    const int wr = (w >> 1) * 64, wc = (w & 1) * 64;
    const int lr = lane & 15, lkg = lane >> 4;
    const int kd = lkg * 8;
    const int rsh   = lane >> 3;
    const int colSw = ((lane & 7) * 8) ^ (rsh << 3);
    const int rBase = 8*w + rsh;

    f32x4 acc[4][4] = {};

#pragma unroll
    for (int i = 0; i < 4; ++i) {
        const int r = rBase + 32*i;
        gll16(A + (size_t)(row0 + r)*HID + colSw, &Al[i*2048 + w*512]);
        gll16(W + (size_t)(col0 + r)*HID + colSw, &Bl[i*2048 + w*512]);
    }
    __syncthreads();

    for (int t = 0; t < 16; ++t) {
        const int cur = (t & 1) * 8192;
        const int nxt = 8192 - cur;
        if (t < 15) {
            const int k0 = (t + 1) * 64;
#pragma unroll
            for (int i = 0; i < 4; ++i) {
                const int r = rBase + 32*i;
                gll16(A + (size_t)(row0 + r)*HID + k0 + colSw, &Al[nxt + i*2048 + w*512]);
                gll16(W + (size_t)(col0 + r)*HID + k0 + colSw, &Bl[nxt + i*2048 + w*512]);
            }
        }
#pragma unroll
        for (int ks = 0; ks < 2; ++ks) {
            bf16x8 af[4], bq[4];
#pragma unroll
            for (int i = 0; i < 4; ++i) {
                const int ar = wr + i*16 + lr;
                af[i] = *(const bf16x8*)&Al[cur + ar*64 + ((ks*32 + kd) ^ ((ar & 7) << 3))];
                const int br = wc + i*16 + lr;
                bq[i] = *(const bf16x8*)&Bl[cur + br*64 + ((ks*32 + kd) ^ ((br & 7) << 3))];
            }
#pragma unroll
            for (int i = 0; i < 4; ++i)
#pragma unroll
                for (int j = 0; j < 4; ++j)
                    acc[i][j] = mfma16(af[i], bq[j], acc[i][j]);
        }
        __syncthreads();
    }

    const int rb = lkg * 4;
#pragma unroll
    for (int i = 0; i < 4; ++i) {
#pragma unroll
        for (int j = 0; j < 4; ++j) {
            const int col = col0 + wc + j*16 + lr;
            const int row = row0 + wr + i*16 + rb;
            if (omode == 0) {
                bf16_t* ob = (bf16_t*)outv;
#pragma unroll
                for (int r = 0; r < 4; ++r)
                    ob[(size_t)(row + r) * HID + col] = (bf16_t)acc[i][j][r];
            } else if (omode == 1) {
                const int bb = row >> 11, tt = row & (T_SEQ - 1);
                const int hh = col >> 6,  d = col & 63;
                bf16x4 pk;
#pragma unroll
                for (int r = 0; r < 4; ++r) pk[r] = (bf16_t)acc[i][j][r];
                *(bf16x4*)((bf16_t*)outv + ((size_t)((bb*NH + hh)*HD + d))*T_SEQ + tt) = pk;
            } else {
                float* of = (float*)outv;
#pragma unroll
                for (int r = 0; r < 4; ++r)
                    of[(size_t)(row + r) * HID + col] = acc[i][j][r];
            }
        }
    }
}

// All 4 projection GEMMs in ONE dispatch. 896 logical blocks:
// 0-255 Q | 256-511 K | 512-767 V(transposed out) | 768-895 rel.
__global__ __launch_bounds__(256) void gemm_proj(
    const bf16_t* __restrict__ xb, const bf16_t* __restrict__ pb,
    const bf16_t* __restrict__ wqb, const bf16_t* __restrict__ wkb,
    const bf16_t* __restrict__ wvb, const bf16_t* __restrict__ wrelb,
    bf16_t* __restrict__ qb, bf16_t* __restrict__ kb,
    bf16_t* __restrict__ vtb, bf16_t* __restrict__ rkb)
{
    __shared__ bf16_t Al[2*128*64];
    __shared__ bf16_t Bl[2*128*64];
    const int hw = blockIdx.x;
    const int logical = (hw & 7) * 112 + (hw >> 3);
    const bf16_t* A; const bf16_t* W; void* out; int omode = 0; int l;
    if (logical < 256)      { A = xb; W = wqb;   out = qb;  l = logical; }
    else if (logical < 512) { A = xb; W = wkb;   out = kb;  l = logical - 256; }
    else if (logical < 768) { A = xb; W = wvb;   out = vtb; l = logical - 512; omode = 1; }
    else                    { A = pb; W = wrelb; out = rkb; l = logical - 768; }
    const int row0 = (l >> 3) * 128, col0 = (l & 7) * 128;
    gemm_core(Al, Bl, A, W, out, row0, col0, omode);
}

// Final GEMM: out_f32 = ab @ Wo^T.
__global__ __launch_bounds__(256) void gemm_out(
    const bf16_t* __restrict__ ab, const bf16_t* __restrict__ wob,
    float* __restrict__ outp)
{
    __shared__ bf16_t Al[2*128*64];
    __shared__ bf16_t Bl[2*128*64];
    const int hw = blockIdx.x;
    const int logical = (hw & 7) * 32 + (hw >> 3);
    const int row0 = (logical >> 3) * 128, col0 = (logical & 7) * 128;
    gemm_core(Al, Bl, ab, wob, outp, row0, col0, 2);
}

// Fused rel-shift attention — round-13 structure + round-14 LDS diet to 52KB
// (target: 3 blocks/CU now that arch VGPR=88):
//  * SINGLE shared Rl window buffer. Proof: wave-level branch activity
//    coincides with block-level window activity except exactly s0==t0 (1/32
//    tiles). On that diagonal tile branch2 computes its 10 MFMAs from GLOBAL
//    per-lane fragment loads (divergent but rare; OOB-negative rel rows stay
//    inside d_ws, finite bf16, never gathered since dt>=2 => rel row >= 0).
//    No mid-tile restage, barrier structure unchanged (2/tile).
//  * pl overlaid into pp's memory (per-wave slices, strict in-wave program
//    order: pp write -> pp gather -> pl write -> pl read; may-alias safe).
//  * pp stride 84 -> 80 (gathers still 16 distinct banks: gcd(79,32)=1).
// Exact rel_shift semantics (incl. unmasked upper-triangle leak):
//   s<=t: (q[t]+bv).relk[T-1-(t-s)] | s==t+1: 0 | s>=t+2: (q[t+1]+bv).relk[s-t-2]
// 0.125 scale folded (exactly) into the bf16 q-fragments.
__global__ __launch_bounds__(256) void attn_kernel(
    const bf16_t* __restrict__ Q, const bf16_t* __restrict__ K,
    const bf16_t* __restrict__ VT, const bf16_t* __restrict__ RK,
    const float* __restrict__ bias_u, const float* __restrict__ bias_v,
    bf16_t* __restrict__ AO)
{
    const int hw = blockIdx.x;
    const int logical = (hw & 7) * 128 + (hw >> 3);
    const int tile = logical & 31;
    const int h    = (logical >> 5) & 15;
    const int b    = logical >> 9;

    const int w = threadIdx.x >> 6, lane = threadIdx.x & 63;
    const int t0 = tile * 64;
    const int lr = lane & 15, lkg = lane >> 4;
    const int kd = lkg * 8;

    __shared__ bf16_t Kl[64*64];         //  8 KB
    __shared__ bf16_t Vl[64*64];         //  8 KB
    __shared__ bf16_t Rl[128*64];        // 16 KB (single shared rel window)
    __shared__ float  pp[4][16][80];     // 20 KB (pl overlaid inside)

    const int tb = t0 + w * 16;

    bf16x8 aqu[2], aqv[2], aqv2[2];
    {
        const int t  = tb + lr;
        const int t2 = (t + 1 < T_SEQ) ? t + 1 : T_SEQ - 1;
        const bf16_t* qp  = Q + ((size_t)(b*T_SEQ + t )*NH + h)*HD;
        const bf16_t* qp2 = Q + ((size_t)(b*T_SEQ + t2)*NH + h)*HD;
        const float* bu = bias_u + h*HD;
        const float* bv = bias_v + h*HD;
#pragma unroll
        for (int f = 0; f < 2; ++f) {
            const int k0 = f*32 + kd;
            bf16x8 q1 = *(const bf16x8*)(qp  + k0);
            bf16x8 q2 = *(const bf16x8*)(qp2 + k0);
#pragma unroll
            for (int j = 0; j < 8; ++j) {
                const float fu = bu[k0+j], fv = bv[k0+j];
                aqu [f][j] = (bf16_t)(((float)q1[j] + fu) * 0.125f);
                aqv [f][j] = (bf16_t)(((float)q1[j] + fv) * 0.125f);
                aqv2[f][j] = (bf16_t)(((float)q2[j] + fv) * 0.125f);
            }
        }
    }

    float m_run = -1e30f, l_run = 0.0f;
    f32x4 oacc[4];
    f32x4 zf = {0.f, 0.f, 0.f, 0.f};
#pragma unroll
    for (int nf = 0; nf < 4; ++nf) oacc[nf] = zf;

    // ---- lane-constant LDS read bases (row&7 == lr&7 in all families) ----
    const int lsw = (lr & 7) << 3;
    const bf16_t* KlA = &Kl[lr*64 + (kd ^ lsw)];
    const bf16_t* KlB = &Kl[lr*64 + ((32 + kd) ^ lsw)];
    const bf16_t* VlA = &Vl[lr*64 + (kd ^ lsw)];
    const bf16_t* VlB = &Vl[lr*64 + ((32 + kd) ^ lsw)];
    const int rrow0 = 48 - 16*w + lr;              // rr = rrow0 + 16jf; rr&7 == lr&7
    const bf16_t* RlA = &Rl[rrow0*64 + (kd ^ lsw)];
    const bf16_t* RlB = &Rl[rrow0*64 + ((32 + kd) ^ lsw)];
    const float*  ppb = &pp[w][lr][4*lkg + 15 - lr];   // + 16j + r
    float*        ppw = &pp[w][lr][4*lkg];             // + 16jf (f32x4)
    bf16_t*       plBase = (bf16_t*)&pp[w][0][0];      // pl overlay [16][72]
    bf16_t*       plw = plBase + lr*72 + 4*lkg;        // + 16j (bf16x4)
    const bf16_t* plr = plBase + lr*72;                // + kd / 32+kd

    // ---- gll source pointers, advanced by constant strides per tile ----
    const int rsh   = lane >> 3;
    const int colSw = ((lane & 7) * 8) ^ (rsh << 3);
    const int kvRow = 16*w + rsh;
    const int rRow  = 32*w + rsh;
    const bf16_t* Kg  = K  + (size_t)(b*T_SEQ)*HID + h*HD + (size_t)kvRow*HID + colSw;
    const bf16_t* Vg  = VT + (size_t)((b*NH + h)*HD)*T_SEQ + (size_t)kvRow*T_SEQ + colSw;
    const bf16_t* Rb  = RK + h*HD;
    const bf16_t* R1g = Rb + (ptrdiff_t)(T_SEQ - 64 - t0 + rRow)*HID + colSw;
    const bf16_t* R2g = Rb + (ptrdiff_t)(-65 - t0 + rRow)*HID + colSw;

    for (int s0 = 0; s0 < T_SEQ; s0 += 64) {
        const bool anyB1 = (s0 <= t0 + 63);     // block-uniform
        const bool anyB2 = (s0 >= t0 - 61);

        // ---- STAGE via global_load_lds: K, V, and the ONE active rel window
        __syncthreads();
#pragma unroll
        for (int i = 0; i < 2; ++i) {
            gll16(Kg + (size_t)(8*i)*HID,   &Kl[(2*w + i)*512]);
            gll16(Vg + (size_t)(8*i)*T_SEQ, &Vl[(2*w + i)*512]);
        }
        {
            const bf16_t* Rg = anyB1 ? R1g : R2g;
#pragma unroll
            for (int i = 0; i < 4; ++i)
                gll16(Rg + (size_t)(8*i)*HID, &Rl[(4*w + i)*512]);
        }
        __syncthreads();
        Kg  += (size_t)64*HID;
        Vg  += 64;
        R1g += (size_t)64*HID;
        R2g += (size_t)64*HID;

        // ---- content scores: sc[j][r] = S[s=s0+16j+4lkg+r][q=tb+lr]
        f32x4 sc[4];
#pragma unroll
        for (int j = 0; j < 4; ++j)
            sc[j] = mfma16(*(const bf16x8*)(KlB + j*1024), aqu[1],
                     mfma16(*(const bf16x8*)(KlA + j*1024), aqu[0], zf));

        const int dbase = s0 - tb + 4*lkg - lr;    // dt = dbase + 16j + r

        // ---- branch 1 (s<=t): Rl holds R1 whenever any wave needs it
        if (s0 <= tb + 15) {
#pragma unroll
            for (int jf = 0; jf < 5; ++jf) {
                f32x4 c = mfma16(*(const bf16x8*)(RlB + jf*1024), aqv[1],
                           mfma16(*(const bf16x8*)(RlA + jf*1024), aqv[0], zf));
                *(f32x4*)(ppw + 16*jf) = c;
            }
            if (s0 <= tb - 63) {
#pragma unroll
                for (int j = 0; j < 4; ++j)
#pragma unroll
                    for (int r = 0; r < 4; ++r)
                        sc[j][r] += ppb[16*j + r];
            } else {
#pragma unroll
                for (int j = 0; j < 4; ++j)
#pragma unroll
                    for (int r = 0; r < 4; ++r) {
                        const float v = ppb[16*j + r];
                        sc[j][r] += (dbase + 16*j + r <= 0) ? v : 0.0f;
                    }
            }
        }
        // ---- branch 2 (s>=t+2, query row t+1)
        if (s0 >= tb - 61) {
            if (!anyB1) {                  // Rl holds R2
#pragma unroll
                for (int jf = 0; jf < 5; ++jf) {
                    f32x4 c = mfma16(*(const bf16x8*)(RlB + jf*1024), aqv2[1],
                               mfma16(*(const bf16x8*)(RlA + jf*1024), aqv2[0], zf));
                    *(f32x4*)(ppw + 16*jf) = c;
                }
            } else {                       // diagonal tile (s0==t0): global fallback
#pragma unroll
                for (int jf = 0; jf < 5; ++jf) {
                    const bf16_t* rp = Rb + (ptrdiff_t)(s0 - t0 - 65 + rrow0 + 16*jf)*HID;
                    f32x4 c = mfma16(*(const bf16x8*)(rp + 32 + kd), aqv2[1],
                               mfma16(*(const bf16x8*)(rp + kd), aqv2[0], zf));
                    *(f32x4*)(ppw + 16*jf) = c;
                }
            }
            if (s0 >= tb + 17) {
#pragma unroll
                for (int j = 0; j < 4; ++j)
#pragma unroll
                    for (int r = 0; r < 4; ++r)
                        sc[j][r] += ppb[16*j + r];
            } else {
#pragma unroll
                for (int j = 0; j < 4; ++j)
#pragma unroll
                    for (int r = 0; r < 4; ++r) {
                        const float v = ppb[16*j + r];
                        sc[j][r] += (dbase + 16*j + r >= 2) ? v : 0.0f;
                    }
            }
        }

        // ---- online softmax: row in-lane (16 vals) + 2 shfls
        float mx = fmaxf(fmaxf(fmaxf(sc[0][0], sc[0][1]), fmaxf(sc[0][2], sc[0][3])),
                         fmaxf(fmaxf(sc[1][0], sc[1][1]), fmaxf(sc[1][2], sc[1][3])));
        mx = fmaxf(mx, fmaxf(fmaxf(fmaxf(sc[2][0], sc[2][1]), fmaxf(sc[2][2], sc[2][3])),
                             fmaxf(fmaxf(sc[3][0], sc[3][1]), fmaxf(sc[3][2], sc[3][3]))));
        mx = fmaxf(mx, __shfl_xor(mx, 16, 64));
        mx = fmaxf(mx, __shfl_xor(mx, 32, 64));
        const float mnew = fmaxf(m_run, mx);
        const bool resc = !__all(mx <= m_run);     // exact: if false, fac==1
        float fac = 1.0f;
        if (resc) fac = __expf(m_run - mnew);
        m_run = mnew;
        float sum = 0.0f;
#pragma unroll
        for (int j = 0; j < 4; ++j) {
            bf16x4 pk;
#pragma unroll
            for (int r = 0; r < 4; ++r) {
                const float p = __expf(sc[j][r] - mnew);
                sum += p;
                pk[r] = (bf16_t)p;
            }
            *(bf16x4*)(plw + 16*j) = pk;
        }
        sum += __shfl_xor(sum, 16, 64);
        sum += __shfl_xor(sum, 32, 64);
        l_run = l_run * fac + sum;
        if (resc) {
#pragma unroll
            for (int r = 0; r < 4; ++r) {
                const float facq = __shfl(fac, 4*lkg + r, 64);
#pragma unroll
                for (int nf = 0; nf < 4; ++nf) oacc[nf][r] *= facq;
            }
        }

        // ---- PV: O += P @ V
        bf16x8 pa0 = *(const bf16x8*)(plr + kd);
        bf16x8 pa1 = *(const bf16x8*)(plr + 32 + kd);
#pragma unroll
        for (int nf = 0; nf < 4; ++nf)
            oacc[nf] = mfma16(pa1, *(const bf16x8*)(VlB + nf*1024),
                        mfma16(pa0, *(const bf16x8*)(VlA + nf*1024), oacc[nf]));
    }

    // ---- epilogue
    const float linv = 1.0f / l_run;
#pragma unroll
    for (int r = 0; r < 4; ++r) {
        const float lq = __shfl(linv, 4*lkg + r, 64);
        const int t = tb + 4*lkg + r;
#pragma unroll
        for (int nf = 0; nf < 4; ++nf)
            AO[(size_t)(b*T_SEQ + t)*HID + h*HD + nf*16 + lr] = (bf16_t)(oacc[nf][r] * lq);
    }
}

extern "C" void kernel_launch(void* const* d_in, const int* in_sizes, int n_in,
                              void* d_out, int out_size, void* d_ws, size_t ws_size,
                              hipStream_t stream) {
    const float* x    = (const float*)d_in[0];
    const float* pos  = (const float*)d_in[1];
    const float* Wq   = (const float*)d_in[2];
    const float* Wk   = (const float*)d_in[3];
    const float* Wv   = (const float*)d_in[4];
    const float* Wo   = (const float*)d_in[5];
    const float* Wrel = (const float*)d_in[6];
    const float* bu   = (const float*)d_in[7];
    const float* bv   = (const float*)d_in[8];

    // ws layout (bf16 elems, M1 = 1M):
    //  qb 0-4 | kb 4-8 | vtb 8-12 | rkb 12-14 | ab 14-18 (xb aliases ab) |
    //  pb 18-20 | wqb 20-21 | wkb 21-22 | wvb 22-23 | wob 23-24 | wrelb 24-25
    //  = 50 MiB total.
    bf16_t* ws   = (bf16_t*)d_ws;
    const size_t M1 = 1024u * 1024u;
    bf16_t* qb    = ws;
    bf16_t* kb    = ws + 4*M1;
    bf16_t* vtb   = ws + 8*M1;
    bf16_t* rkb   = ws + 12*M1;
    bf16_t* ab    = ws + 14*M1;
    bf16_t* xb    = ab;
    bf16_t* pb    = ws + 18*M1;
    bf16_t* wqb   = ws + 20*M1;
    bf16_t* wkb   = ws + 21*M1;
    bf16_t* wvb   = ws + 22*M1;
    bf16_t* wob   = ws + 23*M1;
    bf16_t* wrelb = ws + 24*M1;

    cvt_all<<<5632, 256, 0, stream>>>(x, pos, Wq, Wk, Wv, Wo, Wrel,
                                      xb, pb, wqb, wkb, wvb, wob, wrelb);

    gemm_proj<<<896, 256, 0, stream>>>(xb, pb, wqb, wkb, wvb, wrelb,
                                       qb, kb, vtb, rkb);

    attn_kernel<<<1024, 256, 0, stream>>>(qb, kb, vtb, rkb, bu, bv, ab);

    gemm_out<<<256, 256, 0, stream>>>(ab, wob, (float*)d_out);
}

// Round 15
// 229.560 us; speedup vs baseline: 1.0739x; 1.0739x over previous
//
#include <hip/hip_runtime.h>
#include <hip/hip_bf16.h>

#define T_SEQ 2048
#define HID   1024
#define NH    16
#define HD    64
#define NB    2

typedef __bf16 bf16_t;
typedef bf16_t bf16x8 __attribute__((ext_vector_type(8)));
typedef bf16_t bf16x4 __attribute__((ext_vector_type(4)));
typedef float  f32x4  __attribute__((ext_vector_type(4)));

static __device__ __forceinline__ f32x4 mfma16(bf16x8 a, bf16x8 b, f32x4 c) {
    return __builtin_amdgcn_mfma_f32_16x16x32_bf16(a, b, c, 0, 0, 0);
}

// Async global->LDS, 16B per lane (LDS dest wave-uniform base + lane*16;
// per-lane source pre-swizzled so read-side XOR addressing is unchanged).
static __device__ __forceinline__ void gll16(const bf16_t* g, bf16_t* l) {
    __builtin_amdgcn_global_load_lds(
        (const __attribute__((address_space(1))) void*)g,
        (__attribute__((address_space(3))) void*)l, 16, 0, 0);
}

// One-pass f32 -> bf16 conversion of x, pos, and all 5 weights.
__global__ __launch_bounds__(256) void cvt_all(
    const float* __restrict__ x, const float* __restrict__ pos,
    const float* __restrict__ wq, const float* __restrict__ wk,
    const float* __restrict__ wv, const float* __restrict__ wo,
    const float* __restrict__ wrel,
    bf16_t* __restrict__ xb, bf16_t* __restrict__ pb,
    bf16_t* __restrict__ wqb, bf16_t* __restrict__ wkb,
    bf16_t* __restrict__ wvb, bf16_t* __restrict__ wob,
    bf16_t* __restrict__ wrelb)
{
    int blk = blockIdx.x;
    const float* in; bf16_t* out;
    if (blk < 2048)      { in = x;   out = xb; }
    else if (blk < 3072) { in = pos; out = pb; blk -= 2048; }
    else {
        const int wi = (blk - 3072) >> 9; blk = (blk - 3072) & 511;
        switch (wi) {
            case 0:  in = wq;   out = wqb;   break;
            case 1:  in = wk;   out = wkb;   break;
            case 2:  in = wv;   out = wvb;   break;
            case 3:  in = wo;   out = wob;   break;
            default: in = wrel; out = wrelb; break;
        }
    }
    const int i = blk * 256 + threadIdx.x;
    const float4* p = (const float4*)(in + (size_t)i * 8);
    float4 a0 = p[0], a1 = p[1];
    bf16x8 v;
    v[0]=(bf16_t)a0.x; v[1]=(bf16_t)a0.y; v[2]=(bf16_t)a0.z; v[3]=(bf16_t)a0.w;
    v[4]=(bf16_t)a1.x; v[5]=(bf16_t)a1.y; v[6]=(bf16_t)a1.z; v[7]=(bf16_t)a1.w;
    *(bf16x8*)(out + (size_t)i * 8) = v;
}

// Shared 128x128-tile GEMM core (unchanged from round 12 — measured good).
static __device__ __forceinline__ void gemm_core(
    bf16_t* Al, bf16_t* Bl,
    const bf16_t* __restrict__ A, const bf16_t* __restrict__ W,
    void* __restrict__ outv, int row0, int col0, int omode)
{
    const int tid = threadIdx.x;
    const int w = tid >> 6, lane = tid & 63;
    const int wr = (w >> 1) * 64, wc = (w & 1) * 64;
    const int lr = lane & 15, lkg = lane >> 4;
    const int kd = lkg * 8;
    const int rsh   = lane >> 3;
    const int colSw = ((lane & 7) * 8) ^ (rsh << 3);
    const int rBase = 8*w + rsh;

    f32x4 acc[4][4] = {};

#pragma unroll
    for (int i = 0; i < 4; ++i) {
        const int r = rBase + 32*i;
        gll16(A + (size_t)(row0 + r)*HID + colSw, &Al[i*2048 + w*512]);
        gll16(W + (size_t)(col0 + r)*HID + colSw, &Bl[i*2048 + w*512]);
    }
    __syncthreads();

    for (int t = 0; t < 16; ++t) {
        const int cur = (t & 1) * 8192;
        const int nxt = 8192 - cur;
        if (t < 15) {
            const int k0 = (t + 1) * 64;
#pragma unroll
            for (int i = 0; i < 4; ++i) {
                const int r = rBase + 32*i;
                gll16(A + (size_t)(row0 + r)*HID + k0 + colSw, &Al[nxt + i*2048 + w*512]);
                gll16(W + (size_t)(col0 + r)*HID + k0 + colSw, &Bl[nxt + i*2048 + w*512]);
            }
        }
#pragma unroll
        for (int ks = 0; ks < 2; ++ks) {
            bf16x8 af[4], bq[4];
#pragma unroll
            for (int i = 0; i < 4; ++i) {
                const int ar = wr + i*16 + lr;
                af[i] = *(const bf16x8*)&Al[cur + ar*64 + ((ks*32 + kd) ^ ((ar & 7) << 3))];
                const int br = wc + i*16 + lr;
                bq[i] = *(const bf16x8*)&Bl[cur + br*64 + ((ks*32 + kd) ^ ((br & 7) << 3))];
            }
#pragma unroll
            for (int i = 0; i < 4; ++i)
#pragma unroll
                for (int j = 0; j < 4; ++j)
                    acc[i][j] = mfma16(af[i], bq[j], acc[i][j]);
        }
        __syncthreads();
    }

    const int rb = lkg * 4;
#pragma unroll
    for (int i = 0; i < 4; ++i) {
#pragma unroll
        for (int j = 0; j < 4; ++j) {
            const int col = col0 + wc + j*16 + lr;
            const int row = row0 + wr + i*16 + rb;
            if (omode == 0) {
                bf16_t* ob = (bf16_t*)outv;
#pragma unroll
                for (int r = 0; r < 4; ++r)
                    ob[(size_t)(row + r) * HID + col] = (bf16_t)acc[i][j][r];
            } else if (omode == 1) {
                const int bb = row >> 11, tt = row & (T_SEQ - 1);
                const int hh = col >> 6,  d = col & 63;
                bf16x4 pk;
#pragma unroll
                for (int r = 0; r < 4; ++r) pk[r] = (bf16_t)acc[i][j][r];
                *(bf16x4*)((bf16_t*)outv + ((size_t)((bb*NH + hh)*HD + d))*T_SEQ + tt) = pk;
            } else {
                float* of = (float*)outv;
#pragma unroll
                for (int r = 0; r < 4; ++r)
                    of[(size_t)(row + r) * HID + col] = acc[i][j][r];
            }
        }
    }
}

// All 4 projection GEMMs in ONE dispatch. 896 logical blocks:
// 0-255 Q | 256-511 K | 512-767 V(transposed out) | 768-895 rel.
__global__ __launch_bounds__(256) void gemm_proj(
    const bf16_t* __restrict__ xb, const bf16_t* __restrict__ pb,
    const bf16_t* __restrict__ wqb, const bf16_t* __restrict__ wkb,
    const bf16_t* __restrict__ wvb, const bf16_t* __restrict__ wrelb,
    bf16_t* __restrict__ qb, bf16_t* __restrict__ kb,
    bf16_t* __restrict__ vtb, bf16_t* __restrict__ rkb)
{
    __shared__ bf16_t Al[2*128*64];
    __shared__ bf16_t Bl[2*128*64];
    const int hw = blockIdx.x;
    const int logical = (hw & 7) * 112 + (hw >> 3);
    const bf16_t* A; const bf16_t* W; void* out; int omode = 0; int l;
    if (logical < 256)      { A = xb; W = wqb;   out = qb;  l = logical; }
    else if (logical < 512) { A = xb; W = wkb;   out = kb;  l = logical - 256; }
    else if (logical < 768) { A = xb; W = wvb;   out = vtb; l = logical - 512; omode = 1; }
    else                    { A = pb; W = wrelb; out = rkb; l = logical - 768; }
    const int row0 = (l >> 3) * 128, col0 = (l & 7) * 128;
    gemm_core(Al, Bl, A, W, out, row0, col0, omode);
}

// Final GEMM: out_f32 = ab @ Wo^T.
__global__ __launch_bounds__(256) void gemm_out(
    const bf16_t* __restrict__ ab, const bf16_t* __restrict__ wob,
    float* __restrict__ outp)
{
    __shared__ bf16_t Al[2*128*64];
    __shared__ bf16_t Bl[2*128*64];
    const int hw = blockIdx.x;
    const int logical = (hw & 7) * 32 + (hw >> 3);
    const int row0 = (logical >> 3) * 128, col0 = (logical & 7) * 128;
    gemm_core(Al, Bl, ab, wob, outp, row0, col0, 2);
}

// Fused rel-shift attention — round-14 structure with the pp-stride fix:
//  * pp stride BACK to 84 (r14's 80 ≡ 16 mod 32 made the f32x4 pos-window
//    writes 8-way bank-conflicted: lanes lr and lr+2k hit the same 4-bank
//    group; conflicts tripled 7.5M->23.7M and cost ~21us. Stride 84 ≡ 20
//    mod 32 -> lr*20 cycles 8 distinct bank offsets -> 2-way = free; gather
//    reads use stride-1=83 ≡ 19 (odd) -> 16 distinct banks).
//    LDS total 54272 B; 3 x 54272 = 162816 <= 163840 -> still 3 blocks/CU.
//  * SINGLE shared Rl window (diagonal tile s0==t0 uses global fallback for
//    branch2 — 1/32 tiles, divergent but rare; OOB rel rows stay in d_ws).
//  * pl overlaid into pp's per-wave slice (strict in-wave program order).
//  * Lane-constant LDS bases, pointer-increment gll, exact defer-rescale.
// Exact rel_shift semantics (incl. unmasked upper-triangle leak):
//   s<=t: (q[t]+bv).relk[T-1-(t-s)] | s==t+1: 0 | s>=t+2: (q[t+1]+bv).relk[s-t-2]
// 0.125 scale folded (exactly) into the bf16 q-fragments.
__global__ __launch_bounds__(256) void attn_kernel(
    const bf16_t* __restrict__ Q, const bf16_t* __restrict__ K,
    const bf16_t* __restrict__ VT, const bf16_t* __restrict__ RK,
    const float* __restrict__ bias_u, const float* __restrict__ bias_v,
    bf16_t* __restrict__ AO)
{
    const int hw = blockIdx.x;
    const int logical = (hw & 7) * 128 + (hw >> 3);
    const int tile = logical & 31;
    const int h    = (logical >> 5) & 15;
    const int b    = logical >> 9;

    const int w = threadIdx.x >> 6, lane = threadIdx.x & 63;
    const int t0 = tile * 64;
    const int lr = lane & 15, lkg = lane >> 4;
    const int kd = lkg * 8;

    __shared__ bf16_t Kl[64*64];         //  8 KB
    __shared__ bf16_t Vl[64*64];         //  8 KB
    __shared__ bf16_t Rl[128*64];        // 16 KB (single shared rel window)
    __shared__ float  pp[4][16][84];     // 21 KB (pl overlaid inside)

    const int tb = t0 + w * 16;

    bf16x8 aqu[2], aqv[2], aqv2[2];
    {
        const int t  = tb + lr;
        const int t2 = (t + 1 < T_SEQ) ? t + 1 : T_SEQ - 1;
        const bf16_t* qp  = Q + ((size_t)(b*T_SEQ + t )*NH + h)*HD;
        const bf16_t* qp2 = Q + ((size_t)(b*T_SEQ + t2)*NH + h)*HD;
        const float* bu = bias_u + h*HD;
        const float* bv = bias_v + h*HD;
#pragma unroll
        for (int f = 0; f < 2; ++f) {
            const int k0 = f*32 + kd;
            bf16x8 q1 = *(const bf16x8*)(qp  + k0);
            bf16x8 q2 = *(const bf16x8*)(qp2 + k0);
#pragma unroll
            for (int j = 0; j < 8; ++j) {
                const float fu = bu[k0+j], fv = bv[k0+j];
                aqu [f][j] = (bf16_t)(((float)q1[j] + fu) * 0.125f);
                aqv [f][j] = (bf16_t)(((float)q1[j] + fv) * 0.125f);
                aqv2[f][j] = (bf16_t)(((float)q2[j] + fv) * 0.125f);
            }
        }
    }

    float m_run = -1e30f, l_run = 0.0f;
    f32x4 oacc[4];
    f32x4 zf = {0.f, 0.f, 0.f, 0.f};
#pragma unroll
    for (int nf = 0; nf < 4; ++nf) oacc[nf] = zf;

    // ---- lane-constant LDS read bases (row&7 == lr&7 in all families) ----
    const int lsw = (lr & 7) << 3;
    const bf16_t* KlA = &Kl[lr*64 + (kd ^ lsw)];
    const bf16_t* KlB = &Kl[lr*64 + ((32 + kd) ^ lsw)];
    const bf16_t* VlA = &Vl[lr*64 + (kd ^ lsw)];
    const bf16_t* VlB = &Vl[lr*64 + ((32 + kd) ^ lsw)];
    const int rrow0 = 48 - 16*w + lr;              // rr = rrow0 + 16jf; rr&7 == lr&7
    const bf16_t* RlA = &Rl[rrow0*64 + (kd ^ lsw)];
    const bf16_t* RlB = &Rl[rrow0*64 + ((32 + kd) ^ lsw)];
    const float*  ppb = &pp[w][lr][4*lkg + 15 - lr];   // + 16j + r
    float*        ppw = &pp[w][lr][4*lkg];             // + 16jf (f32x4)
    bf16_t*       plBase = (bf16_t*)&pp[w][0][0];      // pl overlay [16][72]
    bf16_t*       plw = plBase + lr*72 + 4*lkg;        // + 16j (bf16x4)
    const bf16_t* plr = plBase + lr*72;                // + kd / 32+kd

    // ---- gll source pointers, advanced by constant strides per tile ----
    const int rsh   = lane >> 3;
    const int colSw = ((lane & 7) * 8) ^ (rsh << 3);
    const int kvRow = 16*w + rsh;
    const int rRow  = 32*w + rsh;
    const bf16_t* Kg  = K  + (size_t)(b*T_SEQ)*HID + h*HD + (size_t)kvRow*HID + colSw;
    const bf16_t* Vg  = VT + (size_t)((b*NH + h)*HD)*T_SEQ + (size_t)kvRow*T_SEQ + colSw;
    const bf16_t* Rb  = RK + h*HD;
    const bf16_t* R1g = Rb + (ptrdiff_t)(T_SEQ - 64 - t0 + rRow)*HID + colSw;
    const bf16_t* R2g = Rb + (ptrdiff_t)(-65 - t0 + rRow)*HID + colSw;

    for (int s0 = 0; s0 < T_SEQ; s0 += 64) {
        const bool anyB1 = (s0 <= t0 + 63);     // block-uniform
        const bool anyB2 = (s0 >= t0 - 61);

        // ---- STAGE via global_load_lds: K, V, and the ONE active rel window
        __syncthreads();
#pragma unroll
        for (int i = 0; i < 2; ++i) {
            gll16(Kg + (size_t)(8*i)*HID,   &Kl[(2*w + i)*512]);
            gll16(Vg + (size_t)(8*i)*T_SEQ, &Vl[(2*w + i)*512]);
        }
        {
            const bf16_t* Rg = anyB1 ? R1g : R2g;
#pragma unroll
            for (int i = 0; i < 4; ++i)
                gll16(Rg + (size_t)(8*i)*HID, &Rl[(4*w + i)*512]);
        }
        __syncthreads();
        Kg  += (size_t)64*HID;
        Vg  += 64;
        R1g += (size_t)64*HID;
        R2g += (size_t)64*HID;

        // ---- content scores: sc[j][r] = S[s=s0+16j+4lkg+r][q=tb+lr]
        f32x4 sc[4];
#pragma unroll
        for (int j = 0; j < 4; ++j)
            sc[j] = mfma16(*(const bf16x8*)(KlB + j*1024), aqu[1],
                     mfma16(*(const bf16x8*)(KlA + j*1024), aqu[0], zf));

        const int dbase = s0 - tb + 4*lkg - lr;    // dt = dbase + 16j + r

        // ---- branch 1 (s<=t): Rl holds R1 whenever any wave needs it
        if (s0 <= tb + 15) {
#pragma unroll
            for (int jf = 0; jf < 5; ++jf) {
                f32x4 c = mfma16(*(const bf16x8*)(RlB + jf*1024), aqv[1],
                           mfma16(*(const bf16x8*)(RlA + jf*1024), aqv[0], zf));
                *(f32x4*)(ppw + 16*jf) = c;
            }
            if (s0 <= tb - 63) {
#pragma unroll
                for (int j = 0; j < 4; ++j)
#pragma unroll
                    for (int r = 0; r < 4; ++r)
                        sc[j][r] += ppb[16*j + r];
            } else {
#pragma unroll
                for (int j = 0; j < 4; ++j)
#pragma unroll
                    for (int r = 0; r < 4; ++r) {
                        const float v = ppb[16*j + r];
                        sc[j][r] += (dbase + 16*j + r <= 0) ? v : 0.0f;
                    }
            }
        }
        // ---- branch 2 (s>=t+2, query row t+1)
        if (s0 >= tb - 61) {
            if (!anyB1) {                  // Rl holds R2
#pragma unroll
                for (int jf = 0; jf < 5; ++jf) {
                    f32x4 c = mfma16(*(const bf16x8*)(RlB + jf*1024), aqv2[1],
                               mfma16(*(const bf16x8*)(RlA + jf*1024), aqv2[0], zf));
                    *(f32x4*)(ppw + 16*jf) = c;
                }
            } else {                       // diagonal tile (s0==t0): global fallback
#pragma unroll
                for (int jf = 0; jf < 5; ++jf) {
                    const bf16_t* rp = Rb + (ptrdiff_t)(s0 - t0 - 65 + rrow0 + 16*jf)*HID;
                    f32x4 c = mfma16(*(const bf16x8*)(rp + 32 + kd), aqv2[1],
                               mfma16(*(const bf16x8*)(rp + kd), aqv2[0], zf));
                    *(f32x4*)(ppw + 16*jf) = c;
                }
            }
            if (s0 >= tb + 17) {
#pragma unroll
                for (int j = 0; j < 4; ++j)
#pragma unroll
                    for (int r = 0; r < 4; ++r)
                        sc[j][r] += ppb[16*j + r];
            } else {
#pragma unroll
                for (int j = 0; j < 4; ++j)
#pragma unroll
                    for (int r = 0; r < 4; ++r) {
                        const float v = ppb[16*j + r];
                        sc[j][r] += (dbase + 16*j + r >= 2) ? v : 0.0f;
                    }
            }
        }

        // ---- online softmax: row in-lane (16 vals) + 2 shfls
        float mx = fmaxf(fmaxf(fmaxf(sc[0][0], sc[0][1]), fmaxf(sc[0][2], sc[0][3])),
                         fmaxf(fmaxf(sc[1][0], sc[1][1]), fmaxf(sc[1][2], sc[1][3])));
        mx = fmaxf(mx, fmaxf(fmaxf(fmaxf(sc[2][0], sc[2][1]), fmaxf(sc[2][2], sc[2][3])),
                             fmaxf(fmaxf(sc[3][0], sc[3][1]), fmaxf(sc[3][2], sc[3][3]))));
        mx = fmaxf(mx, __shfl_xor(mx, 16, 64));
        mx = fmaxf(mx, __shfl_xor(mx, 32, 64));
        const float mnew = fmaxf(m_run, mx);
        const bool resc = !__all(mx <= m_run);     // exact: if false, fac==1
        float fac = 1.0f;
        if (resc) fac = __expf(m_run - mnew);
        m_run = mnew;
        float sum = 0.0f;
#pragma unroll
        for (int j = 0; j < 4; ++j) {
            bf16x4 pk;
#pragma unroll
            for (int r = 0; r < 4; ++r) {
                const float p = __expf(sc[j][r] - mnew);
                sum += p;
                pk[r] = (bf16_t)p;
            }
            *(bf16x4*)(plw + 16*j) = pk;
        }
        sum += __shfl_xor(sum, 16, 64);
        sum += __shfl_xor(sum, 32, 64);
        l_run = l_run * fac + sum;
        if (resc) {
#pragma unroll
            for (int r = 0; r < 4; ++r) {
                const float facq = __shfl(fac, 4*lkg + r, 64);
#pragma unroll
                for (int nf = 0; nf < 4; ++nf) oacc[nf][r] *= facq;
            }
        }

        // ---- PV: O += P @ V
        bf16x8 pa0 = *(const bf16x8*)(plr + kd);
        bf16x8 pa1 = *(const bf16x8*)(plr + 32 + kd);
#pragma unroll
        for (int nf = 0; nf < 4; ++nf)
            oacc[nf] = mfma16(pa1, *(const bf16x8*)(VlB + nf*1024),
                        mfma16(pa0, *(const bf16x8*)(VlA + nf*1024), oacc[nf]));
    }

    // ---- epilogue
    const float linv = 1.0f / l_run;
#pragma unroll
    for (int r = 0; r < 4; ++r) {
        const float lq = __shfl(linv, 4*lkg + r, 64);
        const int t = tb + 4*lkg + r;
#pragma unroll
        for (int nf = 0; nf < 4; ++nf)
            AO[(size_t)(b*T_SEQ + t)*HID + h*HD + nf*16 + lr] = (bf16_t)(oacc[nf][r] * lq);
    }
}

extern "C" void kernel_launch(void* const* d_in, const int* in_sizes, int n_in,
                              void* d_out, int out_size, void* d_ws, size_t ws_size,
                              hipStream_t stream) {
    const float* x    = (const float*)d_in[0];
    const float* pos  = (const float*)d_in[1];
    const float* Wq   = (const float*)d_in[2];
    const float* Wk   = (const float*)d_in[3];
    const float* Wv   = (const float*)d_in[4];
    const float* Wo   = (const float*)d_in[5];
    const float* Wrel = (const float*)d_in[6];
    const float* bu   = (const float*)d_in[7];
    const float* bv   = (const float*)d_in[8];

    // ws layout (bf16 elems, M1 = 1M):
    //  qb 0-4 | kb 4-8 | vtb 8-12 | rkb 12-14 | ab 14-18 (xb aliases ab) |
    //  pb 18-20 | wqb 20-21 | wkb 21-22 | wvb 22-23 | wob 23-24 | wrelb 24-25
    //  = 50 MiB total.
    bf16_t* ws   = (bf16_t*)d_ws;
    const size_t M1 = 1024u * 1024u;
    bf16_t* qb    = ws;
    bf16_t* kb    = ws + 4*M1;
    bf16_t* vtb   = ws + 8*M1;
    bf16_t* rkb   = ws + 12*M1;
    bf16_t* ab    = ws + 14*M1;
    bf16_t* xb    = ab;
    bf16_t* pb    = ws + 18*M1;
    bf16_t* wqb   = ws + 20*M1;
    bf16_t* wkb   = ws + 21*M1;
    bf16_t* wvb   = ws + 22*M1;
    bf16_t* wob   = ws + 23*M1;
    bf16_t* wrelb = ws + 24*M1;

    cvt_all<<<5632, 256, 0, stream>>>(x, pos, Wq, Wk, Wv, Wo, Wrel,
                                      xb, pb, wqb, wkb, wvb, wob, wrelb);

    gemm_proj<<<896, 256, 0, stream>>>(xb, pb, wqb, wkb, wvb, wrelb,
                                       qb, kb, vtb, rkb);

    attn_kernel<<<1024, 256, 0, stream>>>(qb, kb, vtb, rkb, bu, bv, ab);

    gemm_out<<<256, 256, 0, stream>>>(ab, wob, (float*)d_out);
}

// Round 16
// 229.444 us; speedup vs baseline: 1.0744x; 1.0005x over previous
//
#include <hip/hip_runtime.h>
#include <hip/hip_bf16.h>

#define T_SEQ 2048
#define HID   1024
#define NH    16
#define HD    64
#define NB    2

typedef __bf16 bf16_t;
typedef bf16_t bf16x8 __attribute__((ext_vector_type(8)));
typedef bf16_t bf16x4 __attribute__((ext_vector_type(4)));
typedef float  f32x4  __attribute__((ext_vector_type(4)));

static __device__ __forceinline__ f32x4 mfma16(bf16x8 a, bf16x8 b, f32x4 c) {
    return __builtin_amdgcn_mfma_f32_16x16x32_bf16(a, b, c, 0, 0, 0);
}

// Async global->LDS, 16B per lane (LDS dest wave-uniform base + lane*16;
// per-lane source pre-swizzled so read-side XOR addressing is unchanged).
static __device__ __forceinline__ void gll16(const bf16_t* g, bf16_t* l) {
    __builtin_amdgcn_global_load_lds(
        (const __attribute__((address_space(1))) void*)g,
        (__attribute__((address_space(3))) void*)l, 16, 0, 0);
}

// One-pass f32 -> bf16 conversion of x, pos, and all 5 weights.
__global__ __launch_bounds__(256) void cvt_all(
    const float* __restrict__ x, const float* __restrict__ pos,
    const float* __restrict__ wq, const float* __restrict__ wk,
    const float* __restrict__ wv, const float* __restrict__ wo,
    const float* __restrict__ wrel,
    bf16_t* __restrict__ xb, bf16_t* __restrict__ pb,
    bf16_t* __restrict__ wqb, bf16_t* __restrict__ wkb,
    bf16_t* __restrict__ wvb, bf16_t* __restrict__ wob,
    bf16_t* __restrict__ wrelb)
{
    int blk = blockIdx.x;
    const float* in; bf16_t* out;
    if (blk < 2048)      { in = x;   out = xb; }
    else if (blk < 3072) { in = pos; out = pb; blk -= 2048; }
    else {
        const int wi = (blk - 3072) >> 9; blk = (blk - 3072) & 511;
        switch (wi) {
            case 0:  in = wq;   out = wqb;   break;
            case 1:  in = wk;   out = wkb;   break;
            case 2:  in = wv;   out = wvb;   break;
            case 3:  in = wo;   out = wob;   break;
            default: in = wrel; out = wrelb; break;
        }
    }
    const int i = blk * 256 + threadIdx.x;
    const float4* p = (const float4*)(in + (size_t)i * 8);
    float4 a0 = p[0], a1 = p[1];
    bf16x8 v;
    v[0]=(bf16_t)a0.x; v[1]=(bf16_t)a0.y; v[2]=(bf16_t)a0.z; v[3]=(bf16_t)a0.w;
    v[4]=(bf16_t)a1.x; v[5]=(bf16_t)a1.y; v[6]=(bf16_t)a1.z; v[7]=(bf16_t)a1.w;
    *(bf16x8*)(out + (size_t)i * 8) = v;
}

// Shared 128x128-tile GEMM core (unchanged from round 12 — measured good).
static __device__ __forceinline__ void gemm_core(
    bf16_t* Al, bf16_t* Bl,
    const bf16_t* __restrict__ A, const bf16_t* __restrict__ W,
    void* __restrict__ outv, int row0, int col0, int omode)
{
    const int tid = threadIdx.x;
    const int w = tid >> 6, lane = tid & 63;
    const int wr = (w >> 1) * 64, wc = (w & 1) * 64;
    const int lr = lane & 15, lkg = lane >> 4;
    const int kd = lkg * 8;
    const int rsh   = lane >> 3;
    const int colSw = ((lane & 7) * 8) ^ (rsh << 3);
    const int rBase = 8*w + rsh;

    f32x4 acc[4][4] = {};

#pragma unroll
    for (int i = 0; i < 4; ++i) {
        const int r = rBase + 32*i;
        gll16(A + (size_t)(row0 + r)*HID + colSw, &Al[i*2048 + w*512]);
        gll16(W + (size_t)(col0 + r)*HID + colSw, &Bl[i*2048 + w*512]);
    }
    __syncthreads();

    for (int t = 0; t < 16; ++t) {
        const int cur = (t & 1) * 8192;
        const int nxt = 8192 - cur;
        if (t < 15) {
            const int k0 = (t + 1) * 64;
#pragma unroll
            for (int i = 0; i < 4; ++i) {
                const int r = rBase + 32*i;
                gll16(A + (size_t)(row0 + r)*HID + k0 + colSw, &Al[nxt + i*2048 + w*512]);
                gll16(W + (size_t)(col0 + r)*HID + k0 + colSw, &Bl[nxt + i*2048 + w*512]);
            }
        }
#pragma unroll
        for (int ks = 0; ks < 2; ++ks) {
            bf16x8 af[4], bq[4];
#pragma unroll
            for (int i = 0; i < 4; ++i) {
                const int ar = wr + i*16 + lr;
                af[i] = *(const bf16x8*)&Al[cur + ar*64 + ((ks*32 + kd) ^ ((ar & 7) << 3))];
                const int br = wc + i*16 + lr;
                bq[i] = *(const bf16x8*)&Bl[cur + br*64 + ((ks*32 + kd) ^ ((br & 7) << 3))];
            }
#pragma unroll
            for (int i = 0; i < 4; ++i)
#pragma unroll
                for (int j = 0; j < 4; ++j)
                    acc[i][j] = mfma16(af[i], bq[j], acc[i][j]);
        }
        __syncthreads();
    }

    const int rb = lkg * 4;
#pragma unroll
    for (int i = 0; i < 4; ++i) {
#pragma unroll
        for (int j = 0; j < 4; ++j) {
            const int col = col0 + wc + j*16 + lr;
            const int row = row0 + wr + i*16 + rb;
            if (omode == 0) {
                bf16_t* ob = (bf16_t*)outv;
#pragma unroll
                for (int r = 0; r < 4; ++r)
                    ob[(size_t)(row + r) * HID + col] = (bf16_t)acc[i][j][r];
            } else if (omode == 1) {
                const int bb = row >> 11, tt = row & (T_SEQ - 1);
                const int hh = col >> 6,  d = col & 63;
                bf16x4 pk;
#pragma unroll
                for (int r = 0; r < 4; ++r) pk[r] = (bf16_t)acc[i][j][r];
                *(bf16x4*)((bf16_t*)outv + ((size_t)((bb*NH + hh)*HD + d))*T_SEQ + tt) = pk;
            } else {
                float* of = (float*)outv;
#pragma unroll
                for (int r = 0; r < 4; ++r)
                    of[(size_t)(row + r) * HID + col] = acc[i][j][r];
            }
        }
    }
}

// All 4 projection GEMMs in ONE dispatch. 896 logical blocks:
// 0-255 Q | 256-511 K | 512-767 V(transposed out) | 768-895 rel.
__global__ __launch_bounds__(256) void gemm_proj(
    const bf16_t* __restrict__ xb, const bf16_t* __restrict__ pb,
    const bf16_t* __restrict__ wqb, const bf16_t* __restrict__ wkb,
    const bf16_t* __restrict__ wvb, const bf16_t* __restrict__ wrelb,
    bf16_t* __restrict__ qb, bf16_t* __restrict__ kb,
    bf16_t* __restrict__ vtb, bf16_t* __restrict__ rkb)
{
    __shared__ bf16_t Al[2*128*64];
    __shared__ bf16_t Bl[2*128*64];
    const int hw = blockIdx.x;
    const int logical = (hw & 7) * 112 + (hw >> 3);
    const bf16_t* A; const bf16_t* W; void* out; int omode = 0; int l;
    if (logical < 256)      { A = xb; W = wqb;   out = qb;  l = logical; }
    else if (logical < 512) { A = xb; W = wkb;   out = kb;  l = logical - 256; }
    else if (logical < 768) { A = xb; W = wvb;   out = vtb; l = logical - 512; omode = 1; }
    else                    { A = pb; W = wrelb; out = rkb; l = logical - 768; }
    const int row0 = (l >> 3) * 128, col0 = (l & 7) * 128;
    gemm_core(Al, Bl, A, W, out, row0, col0, omode);
}

// Final GEMM: out_f32 = ab @ Wo^T.
__global__ __launch_bounds__(256) void gemm_out(
    const bf16_t* __restrict__ ab, const bf16_t* __restrict__ wob,
    float* __restrict__ outp)
{
    __shared__ bf16_t Al[2*128*64];
    __shared__ bf16_t Bl[2*128*64];
    const int hw = blockIdx.x;
    const int logical = (hw & 7) * 32 + (hw >> 3);
    const int row0 = (logical >> 3) * 128, col0 = (logical & 7) * 128;
    gemm_core(Al, Bl, ab, wob, outp, row0, col0, 2);
}

// Fused rel-shift attention — round-15 structure + round-16 pp XOR-swizzle:
//  * pp back to stride 80 (LDS = 53248 = the proven 3-blocks/CU size with
//    VGPR<=80; 54272 did NOT fit — runtime reserves ~1KB of the 160KB).
//    Conflict-free via XOR instead of pad: phys col = col ^ xk4,
//    xk4 = ((lr>>1)&3)<<2. xk4<16 flips only bits 2-3 -> f32x4 writes stay
//    16B-aligned, consecutive, and in-row (no overflow past col 79).
//    Write banks: 16lr+4((lr>>1)&3) mod 32 -> 8 distinct, 2-way = free.
//    Gather banks (enumerated): 16 distinct. Cost: 1 v_xor per gather.
//  * SINGLE shared Rl window (diagonal tile s0==t0: global fallback for
//    branch2, 1/32 tiles). pl overlaid in pp slice. Lane-const LDS bases,
//    pointer-increment gll, exact defer-rescale. NSPLIT=1.
// Exact rel_shift semantics (incl. unmasked upper-triangle leak):
//   s<=t: (q[t]+bv).relk[T-1-(t-s)] | s==t+1: 0 | s>=t+2: (q[t+1]+bv).relk[s-t-2]
// 0.125 scale folded (exactly) into the bf16 q-fragments.
__global__ __launch_bounds__(256) void attn_kernel(
    const bf16_t* __restrict__ Q, const bf16_t* __restrict__ K,
    const bf16_t* __restrict__ VT, const bf16_t* __restrict__ RK,
    const float* __restrict__ bias_u, const float* __restrict__ bias_v,
    bf16_t* __restrict__ AO)
{
    const int hw = blockIdx.x;
    const int logical = (hw & 7) * 128 + (hw >> 3);
    const int tile = logical & 31;
    const int h    = (logical >> 5) & 15;
    const int b    = logical >> 9;

    const int w = threadIdx.x >> 6, lane = threadIdx.x & 63;
    const int t0 = tile * 64;
    const int lr = lane & 15, lkg = lane >> 4;
    const int kd = lkg * 8;

    __shared__ bf16_t Kl[64*64];         //  8 KB
    __shared__ bf16_t Vl[64*64];         //  8 KB
    __shared__ bf16_t Rl[128*64];        // 16 KB (single shared rel window)
    __shared__ float  pp[4][16][80];     // 20 KB, XOR-swizzled (pl overlaid)

    const int tb = t0 + w * 16;

    bf16x8 aqu[2], aqv[2], aqv2[2];
    {
        const int t  = tb + lr;
        const int t2 = (t + 1 < T_SEQ) ? t + 1 : T_SEQ - 1;
        const bf16_t* qp  = Q + ((size_t)(b*T_SEQ + t )*NH + h)*HD;
        const bf16_t* qp2 = Q + ((size_t)(b*T_SEQ + t2)*NH + h)*HD;
        const float* bu = bias_u + h*HD;
        const float* bv = bias_v + h*HD;
#pragma unroll
        for (int f = 0; f < 2; ++f) {
            const int k0 = f*32 + kd;
            bf16x8 q1 = *(const bf16x8*)(qp  + k0);
            bf16x8 q2 = *(const bf16x8*)(qp2 + k0);
#pragma unroll
            for (int j = 0; j < 8; ++j) {
                const float fu = bu[k0+j], fv = bv[k0+j];
                aqu [f][j] = (bf16_t)(((float)q1[j] + fu) * 0.125f);
                aqv [f][j] = (bf16_t)(((float)q1[j] + fv) * 0.125f);
                aqv2[f][j] = (bf16_t)(((float)q2[j] + fv) * 0.125f);
            }
        }
    }

    float m_run = -1e30f, l_run = 0.0f;
    f32x4 oacc[4];
    f32x4 zf = {0.f, 0.f, 0.f, 0.f};
#pragma unroll
    for (int nf = 0; nf < 4; ++nf) oacc[nf] = zf;

    // ---- lane-constant LDS read bases (row&7 == lr&7 in all families) ----
    const int lsw = (lr & 7) << 3;
    const bf16_t* KlA = &Kl[lr*64 + (kd ^ lsw)];
    const bf16_t* KlB = &Kl[lr*64 + ((32 + kd) ^ lsw)];
    const bf16_t* VlA = &Vl[lr*64 + (kd ^ lsw)];
    const bf16_t* VlB = &Vl[lr*64 + ((32 + kd) ^ lsw)];
    const int rrow0 = 48 - 16*w + lr;              // rr = rrow0 + 16jf; rr&7 == lr&7
    const bf16_t* RlA = &Rl[rrow0*64 + (kd ^ lsw)];
    const bf16_t* RlB = &Rl[rrow0*64 + ((32 + kd) ^ lsw)];
    // pp XOR swizzle key (flips bits 2-3 only)
    const int xk4 = ((lr >> 1) & 3) << 2;
    float*        ppw  = &pp[w][lr][(4*lkg) ^ xk4];    // + 16jf (f32x4 writes)
    const float*  ppr  = &pp[w][lr][0];                // gather: [(cbase+16j+r)^xk4]
    const int     cbase = 4*lkg + 15 - lr;
    bf16_t*       plBase = (bf16_t*)&pp[w][0][0];      // pl overlay [16][72]
    bf16_t*       plw = plBase + lr*72 + 4*lkg;        // + 16j (bf16x4)
    const bf16_t* plr = plBase + lr*72;                // + kd / 32+kd

    // ---- gll source pointers, advanced by constant strides per tile ----
    const int rsh   = lane >> 3;
    const int colSw = ((lane & 7) * 8) ^ (rsh << 3);
    const int kvRow = 16*w + rsh;
    const int rRow  = 32*w + rsh;
    const bf16_t* Kg  = K  + (size_t)(b*T_SEQ)*HID + h*HD + (size_t)kvRow*HID + colSw;
    const bf16_t* Vg  = VT + (size_t)((b*NH + h)*HD)*T_SEQ + (size_t)kvRow*T_SEQ + colSw;
    const bf16_t* Rb  = RK + h*HD;
    const bf16_t* R1g = Rb + (ptrdiff_t)(T_SEQ - 64 - t0 + rRow)*HID + colSw;
    const bf16_t* R2g = Rb + (ptrdiff_t)(-65 - t0 + rRow)*HID + colSw;

    for (int s0 = 0; s0 < T_SEQ; s0 += 64) {
        const bool anyB1 = (s0 <= t0 + 63);     // block-uniform
        const bool anyB2 = (s0 >= t0 - 61);

        // ---- STAGE via global_load_lds: K, V, and the ONE active rel window
        __syncthreads();
#pragma unroll
        for (int i = 0; i < 2; ++i) {
            gll16(Kg + (size_t)(8*i)*HID,   &Kl[(2*w + i)*512]);
            gll16(Vg + (size_t)(8*i)*T_SEQ, &Vl[(2*w + i)*512]);
        }
        {
            const bf16_t* Rg = anyB1 ? R1g : R2g;
#pragma unroll
            for (int i = 0; i < 4; ++i)
                gll16(Rg + (size_t)(8*i)*HID, &Rl[(4*w + i)*512]);
        }
        __syncthreads();
        Kg  += (size_t)64*HID;
        Vg  += 64;
        R1g += (size_t)64*HID;
        R2g += (size_t)64*HID;

        // ---- content scores: sc[j][r] = S[s=s0+16j+4lkg+r][q=tb+lr]
        f32x4 sc[4];
#pragma unroll
        for (int j = 0; j < 4; ++j)
            sc[j] = mfma16(*(const bf16x8*)(KlB + j*1024), aqu[1],
                     mfma16(*(const bf16x8*)(KlA + j*1024), aqu[0], zf));

        const int dbase = s0 - tb + 4*lkg - lr;    // dt = dbase + 16j + r

        // ---- branch 1 (s<=t): Rl holds R1 whenever any wave needs it
        if (s0 <= tb + 15) {
#pragma unroll
            for (int jf = 0; jf < 5; ++jf) {
                f32x4 c = mfma16(*(const bf16x8*)(RlB + jf*1024), aqv[1],
                           mfma16(*(const bf16x8*)(RlA + jf*1024), aqv[0], zf));
                *(f32x4*)(ppw + 16*jf) = c;
            }
            if (s0 <= tb - 63) {
#pragma unroll
                for (int j = 0; j < 4; ++j)
#pragma unroll
                    for (int r = 0; r < 4; ++r)
                        sc[j][r] += ppr[(cbase + 16*j + r) ^ xk4];
            } else {
#pragma unroll
                for (int j = 0; j < 4; ++j)
#pragma unroll
                    for (int r = 0; r < 4; ++r) {
                        const float v = ppr[(cbase + 16*j + r) ^ xk4];
                        sc[j][r] += (dbase + 16*j + r <= 0) ? v : 0.0f;
                    }
            }
        }
        // ---- branch 2 (s>=t+2, query row t+1)
        if (s0 >= tb - 61) {
            if (!anyB1) {                  // Rl holds R2
#pragma unroll
                for (int jf = 0; jf < 5; ++jf) {
                    f32x4 c = mfma16(*(const bf16x8*)(RlB + jf*1024), aqv2[1],
                               mfma16(*(const bf16x8*)(RlA + jf*1024), aqv2[0], zf));
                    *(f32x4*)(ppw + 16*jf) = c;
                }
            } else {                       // diagonal tile (s0==t0): global fallback
#pragma unroll
                for (int jf = 0; jf < 5; ++jf) {
                    const bf16_t* rp = Rb + (ptrdiff_t)(s0 - t0 - 65 + rrow0 + 16*jf)*HID;
                    f32x4 c = mfma16(*(const bf16x8*)(rp + 32 + kd), aqv2[1],
                               mfma16(*(const bf16x8*)(rp + kd), aqv2[0], zf));
                    *(f32x4*)(ppw + 16*jf) = c;
                }
            }
            if (s0 >= tb + 17) {
#pragma unroll
                for (int j = 0; j < 4; ++j)
#pragma unroll
                    for (int r = 0; r < 4; ++r)
                        sc[j][r] += ppr[(cbase + 16*j + r) ^ xk4];
            } else {
#pragma unroll
                for (int j = 0; j < 4; ++j)
#pragma unroll
                    for (int r = 0; r < 4; ++r) {
                        const float v = ppr[(cbase + 16*j + r) ^ xk4];
                        sc[j][r] += (dbase + 16*j + r >= 2) ? v : 0.0f;
                    }
            }
        }

        // ---- online softmax: row in-lane (16 vals) + 2 shfls
        float mx = fmaxf(fmaxf(fmaxf(sc[0][0], sc[0][1]), fmaxf(sc[0][2], sc[0][3])),
                         fmaxf(fmaxf(sc[1][0], sc[1][1]), fmaxf(sc[1][2], sc[1][3])));
        mx = fmaxf(mx, fmaxf(fmaxf(fmaxf(sc[2][0], sc[2][1]), fmaxf(sc[2][2], sc[2][3])),
                             fmaxf(fmaxf(sc[3][0], sc[3][1]), fmaxf(sc[3][2], sc[3][3]))));
        mx = fmaxf(mx, __shfl_xor(mx, 16, 64));
        mx = fmaxf(mx, __shfl_xor(mx, 32, 64));
        const float mnew = fmaxf(m_run, mx);
        const bool resc = !__all(mx <= m_run);     // exact: if false, fac==1
        float fac = 1.0f;
        if (resc) fac = __expf(m_run - mnew);
        m_run = mnew;
        float sum = 0.0f;
#pragma unroll
        for (int j = 0; j < 4; ++j) {
            bf16x4 pk;
#pragma unroll
            for (int r = 0; r < 4; ++r) {
                const float p = __expf(sc[j][r] - mnew);
                sum += p;
                pk[r] = (bf16_t)p;
            }
            *(bf16x4*)(plw + 16*j) = pk;
        }
        sum += __shfl_xor(sum, 16, 64);
        sum += __shfl_xor(sum, 32, 64);
        l_run = l_run * fac + sum;
        if (resc) {
#pragma unroll
            for (int r = 0; r < 4; ++r) {
                const float facq = __shfl(fac, 4*lkg + r, 64);
#pragma unroll
                for (int nf = 0; nf < 4; ++nf) oacc[nf][r] *= facq;
            }
        }

        // ---- PV: O += P @ V
        bf16x8 pa0 = *(const bf16x8*)(plr + kd);
        bf16x8 pa1 = *(const bf16x8*)(plr + 32 + kd);
#pragma unroll
        for (int nf = 0; nf < 4; ++nf)
            oacc[nf] = mfma16(pa1, *(const bf16x8*)(VlB + nf*1024),
                        mfma16(pa0, *(const bf16x8*)(VlA + nf*1024), oacc[nf]));
    }

    // ---- epilogue
    const float linv = 1.0f / l_run;
#pragma unroll
    for (int r = 0; r < 4; ++r) {
        const float lq = __shfl(linv, 4*lkg + r, 64);
        const int t = tb + 4*lkg + r;
#pragma unroll
        for (int nf = 0; nf < 4; ++nf)
            AO[(size_t)(b*T_SEQ + t)*HID + h*HD + nf*16 + lr] = (bf16_t)(oacc[nf][r] * lq);
    }
}

extern "C" void kernel_launch(void* const* d_in, const int* in_sizes, int n_in,
                              void* d_out, int out_size, void* d_ws, size_t ws_size,
                              hipStream_t stream) {
    const float* x    = (const float*)d_in[0];
    const float* pos  = (const float*)d_in[1];
    const float* Wq   = (const float*)d_in[2];
    const float* Wk   = (const float*)d_in[3];
    const float* Wv   = (const float*)d_in[4];
    const float* Wo   = (const float*)d_in[5];
    const float* Wrel = (const float*)d_in[6];
    const float* bu   = (const float*)d_in[7];
    const float* bv   = (const float*)d_in[8];

    // ws layout (bf16 elems, M1 = 1M):
    //  qb 0-4 | kb 4-8 | vtb 8-12 | rkb 12-14 | ab 14-18 (xb aliases ab) |
    //  pb 18-20 | wqb 20-21 | wkb 21-22 | wvb 22-23 | wob 23-24 | wrelb 24-25
    //  = 50 MiB total.
    bf16_t* ws   = (bf16_t*)d_ws;
    const size_t M1 = 1024u * 1024u;
    bf16_t* qb    = ws;
    bf16_t* kb    = ws + 4*M1;
    bf16_t* vtb   = ws + 8*M1;
    bf16_t* rkb   = ws + 12*M1;
    bf16_t* ab    = ws + 14*M1;
    bf16_t* xb    = ab;
    bf16_t* pb    = ws + 18*M1;
    bf16_t* wqb   = ws + 20*M1;
    bf16_t* wkb   = ws + 21*M1;
    bf16_t* wvb   = ws + 22*M1;
    bf16_t* wob   = ws + 23*M1;
    bf16_t* wrelb = ws + 24*M1;

    cvt_all<<<5632, 256, 0, stream>>>(x, pos, Wq, Wk, Wv, Wo, Wrel,
                                      xb, pb, wqb, wkb, wvb, wob, wrelb);

    gemm_proj<<<896, 256, 0, stream>>>(xb, pb, wqb, wkb, wvb, wrelb,
                                       qb, kb, vtb, rkb);

    attn_kernel<<<1024, 256, 0, stream>>>(qb, kb, vtb, rkb, bu, bv, ab);

    gemm_out<<<256, 256, 0, stream>>>(ab, wob, (float*)d_out);
}

// Round 17
// 226.942 us; speedup vs baseline: 1.0863x; 1.0110x over previous
//
#include <hip/hip_runtime.h>
#include <hip/hip_bf16.h>

#define T_SEQ 2048
#define HID   1024
#define NH    16
#define HD    64
#define NB    2

typedef __bf16 bf16_t;
typedef bf16_t bf16x8 __attribute__((ext_vector_type(8)));
typedef bf16_t bf16x4 __attribute__((ext_vector_type(4)));
typedef float  f32x4  __attribute__((ext_vector_type(4)));

static __device__ __forceinline__ f32x4 mfma16(bf16x8 a, bf16x8 b, f32x4 c) {
    return __builtin_amdgcn_mfma_f32_16x16x32_bf16(a, b, c, 0, 0, 0);
}

// Async global->LDS, 16B per lane (LDS dest wave-uniform base + lane*16;
// per-lane source pre-swizzled so read-side XOR addressing is unchanged).
static __device__ __forceinline__ void gll16(const bf16_t* g, bf16_t* l) {
    __builtin_amdgcn_global_load_lds(
        (const __attribute__((address_space(1))) void*)g,
        (__attribute__((address_space(3))) void*)l, 16, 0, 0);
}

// One-pass f32 -> bf16 conversion of x, pos, and all 5 weights.
__global__ __launch_bounds__(256) void cvt_all(
    const float* __restrict__ x, const float* __restrict__ pos,
    const float* __restrict__ wq, const float* __restrict__ wk,
    const float* __restrict__ wv, const float* __restrict__ wo,
    const float* __restrict__ wrel,
    bf16_t* __restrict__ xb, bf16_t* __restrict__ pb,
    bf16_t* __restrict__ wqb, bf16_t* __restrict__ wkb,
    bf16_t* __restrict__ wvb, bf16_t* __restrict__ wob,
    bf16_t* __restrict__ wrelb)
{
    int blk = blockIdx.x;
    const float* in; bf16_t* out;
    if (blk < 2048)      { in = x;   out = xb; }
    else if (blk < 3072) { in = pos; out = pb; blk -= 2048; }
    else {
        const int wi = (blk - 3072) >> 9; blk = (blk - 3072) & 511;
        switch (wi) {
            case 0:  in = wq;   out = wqb;   break;
            case 1:  in = wk;   out = wkb;   break;
            case 2:  in = wv;   out = wvb;   break;
            case 3:  in = wo;   out = wob;   break;
            default: in = wrel; out = wrelb; break;
        }
    }
    const int i = blk * 256 + threadIdx.x;
    const float4* p = (const float4*)(in + (size_t)i * 8);
    float4 a0 = p[0], a1 = p[1];
    bf16x8 v;
    v[0]=(bf16_t)a0.x; v[1]=(bf16_t)a0.y; v[2]=(bf16_t)a0.z; v[3]=(bf16_t)a0.w;
    v[4]=(bf16_t)a1.x; v[5]=(bf16_t)a1.y; v[6]=(bf16_t)a1.z; v[7]=(bf16_t)a1.w;
    *(bf16x8*)(out + (size_t)i * 8) = v;
}

// Shared 128x128-tile GEMM core (round-12 version — measured good).
static __device__ __forceinline__ void gemm_core(
    bf16_t* Al, bf16_t* Bl,
    const bf16_t* __restrict__ A, const bf16_t* __restrict__ W,
    void* __restrict__ outv, int row0, int col0, int omode)
{
    const int tid = threadIdx.x;
    const int w = tid >> 6, lane = tid & 63;
    const int wr = (w >> 1) * 64, wc = (w & 1) * 64;
    const int lr = lane & 15, lkg = lane >> 4;
    const int kd = lkg * 8;
    const int rsh   = lane >> 3;
    const int colSw = ((lane & 7) * 8) ^ (rsh << 3);
    const int rBase = 8*w + rsh;

    f32x4 acc[4][4] = {};

#pragma unroll
    for (int i = 0; i < 4; ++i) {
        const int r = rBase + 32*i;
        gll16(A + (size_t)(row0 + r)*HID + colSw, &Al[i*2048 + w*512]);
        gll16(W + (size_t)(col0 + r)*HID + colSw, &Bl[i*2048 + w*512]);
    }
    __syncthreads();

    for (int t = 0; t < 16; ++t) {
        const int cur = (t & 1) * 8192;
        const int nxt = 8192 - cur;
        if (t < 15) {
            const int k0 = (t + 1) * 64;
#pragma unroll
            for (int i = 0; i < 4; ++i) {
                const int r = rBase + 32*i;
                gll16(A + (size_t)(row0 + r)*HID + k0 + colSw, &Al[nxt + i*2048 + w*512]);
                gll16(W + (size_t)(col0 + r)*HID + k0 + colSw, &Bl[nxt + i*2048 + w*512]);
            }
        }
#pragma unroll
        for (int ks = 0; ks < 2; ++ks) {
            bf16x8 af[4], bq[4];
#pragma unroll
            for (int i = 0; i < 4; ++i) {
                const int ar = wr + i*16 + lr;
                af[i] = *(const bf16x8*)&Al[cur + ar*64 + ((ks*32 + kd) ^ ((ar & 7) << 3))];
                const int br = wc + i*16 + lr;
                bq[i] = *(const bf16x8*)&Bl[cur + br*64 + ((ks*32 + kd) ^ ((br & 7) << 3))];
            }
#pragma unroll
            for (int i = 0; i < 4; ++i)
#pragma unroll
                for (int j = 0; j < 4; ++j)
                    acc[i][j] = mfma16(af[i], bq[j], acc[i][j]);
        }
        __syncthreads();
    }

    const int rb = lkg * 4;
#pragma unroll
    for (int i = 0; i < 4; ++i) {
#pragma unroll
        for (int j = 0; j < 4; ++j) {
            const int col = col0 + wc + j*16 + lr;
            const int row = row0 + wr + i*16 + rb;
            if (omode == 0) {
                bf16_t* ob = (bf16_t*)outv;
#pragma unroll
                for (int r = 0; r < 4; ++r)
                    ob[(size_t)(row + r) * HID + col] = (bf16_t)acc[i][j][r];
            } else if (omode == 1) {
                const int bb = row >> 11, tt = row & (T_SEQ - 1);
                const int hh = col >> 6,  d = col & 63;
                bf16x4 pk;
#pragma unroll
                for (int r = 0; r < 4; ++r) pk[r] = (bf16_t)acc[i][j][r];
                *(bf16x4*)((bf16_t*)outv + ((size_t)((bb*NH + hh)*HD + d))*T_SEQ + tt) = pk;
            } else {
                float* of = (float*)outv;
#pragma unroll
                for (int r = 0; r < 4; ++r)
                    of[(size_t)(row + r) * HID + col] = acc[i][j][r];
            }
        }
    }
}

// All 4 projection GEMMs in ONE dispatch. 896 logical blocks:
// 0-255 Q | 256-511 K | 512-767 V(transposed out) | 768-895 rel.
__global__ __launch_bounds__(256) void gemm_proj(
    const bf16_t* __restrict__ xb, const bf16_t* __restrict__ pb,
    const bf16_t* __restrict__ wqb, const bf16_t* __restrict__ wkb,
    const bf16_t* __restrict__ wvb, const bf16_t* __restrict__ wrelb,
    bf16_t* __restrict__ qb, bf16_t* __restrict__ kb,
    bf16_t* __restrict__ vtb, bf16_t* __restrict__ rkb)
{
    __shared__ bf16_t Al[2*128*64];
    __shared__ bf16_t Bl[2*128*64];
    const int hw = blockIdx.x;
    const int logical = (hw & 7) * 112 + (hw >> 3);
    const bf16_t* A; const bf16_t* W; void* out; int omode = 0; int l;
    if (logical < 256)      { A = xb; W = wqb;   out = qb;  l = logical; }
    else if (logical < 512) { A = xb; W = wkb;   out = kb;  l = logical - 256; }
    else if (logical < 768) { A = xb; W = wvb;   out = vtb; l = logical - 512; omode = 1; }
    else                    { A = pb; W = wrelb; out = rkb; l = logical - 768; }
    const int row0 = (l >> 3) * 128, col0 = (l & 7) * 128;
    gemm_core(Al, Bl, A, W, out, row0, col0, omode);
}

// Final GEMM: out_f32 = ab @ Wo^T.
__global__ __launch_bounds__(256) void gemm_out(
    const bf16_t* __restrict__ ab, const bf16_t* __restrict__ wob,
    float* __restrict__ outp)
{
    __shared__ bf16_t Al[2*128*64];
    __shared__ bf16_t Bl[2*128*64];
    const int hw = blockIdx.x;
    const int logical = (hw & 7) * 32 + (hw >> 3);
    const int row0 = (logical >> 3) * 128, col0 = (logical & 7) * 128;
    gemm_core(Al, Bl, ab, wob, outp, row0, col0, 2);
}

// Fused rel-shift attention — ROUND-13 CONFIGURATION RESTORED (best measured:
// attn 155.5us, total 227.0us). Separate R1l/R2l (no diagonal fallback),
// f32 pp stride 84, separate pl, LDS 79872 (2 blocks/CU), lane-constant LDS
// bases + immediate offsets, pointer-increment gll, exact defer-rescale,
// NSPLIT=1. Rounds 14-16 proved: 3-blocks/CU occupancy (26%) gives ZERO
// speedup -> the kernel sits at a latency-structure floor, and this 2-block
// config is the fastest measured point of the design.
// Exact rel_shift semantics (incl. unmasked upper-triangle leak):
//   s<=t: (q[t]+bv).relk[T-1-(t-s)] | s==t+1: 0 | s>=t+2: (q[t+1]+bv).relk[s-t-2]
// 0.125 scale folded (exactly) into the bf16 q-fragments.
__global__ __launch_bounds__(256) void attn_kernel(
    const bf16_t* __restrict__ Q, const bf16_t* __restrict__ K,
    const bf16_t* __restrict__ VT, const bf16_t* __restrict__ RK,
    const float* __restrict__ bias_u, const float* __restrict__ bias_v,
    bf16_t* __restrict__ AO)
{
    const int hw = blockIdx.x;
    const int logical = (hw & 7) * 128 + (hw >> 3);
    const int tile = logical & 31;
    const int h    = (logical >> 5) & 15;
    const int b    = logical >> 9;

    const int w = threadIdx.x >> 6, lane = threadIdx.x & 63;
    const int t0 = tile * 64;
    const int lr = lane & 15, lkg = lane >> 4;
    const int kd = lkg * 8;

    __shared__ bf16_t Kl[64*64];
    __shared__ bf16_t Vl[64*64];
    __shared__ bf16_t R1l[128*64];
    __shared__ bf16_t R2l[128*64];
    __shared__ float  pp[4][16][84];
    __shared__ bf16_t pl[4][16][72];

    const int tb = t0 + w * 16;

    bf16x8 aqu[2], aqv[2], aqv2[2];
    {
        const int t  = tb + lr;
        const int t2 = (t + 1 < T_SEQ) ? t + 1 : T_SEQ - 1;
        const bf16_t* qp  = Q + ((size_t)(b*T_SEQ + t )*NH + h)*HD;
        const bf16_t* qp2 = Q + ((size_t)(b*T_SEQ + t2)*NH + h)*HD;
        const float* bu = bias_u + h*HD;
        const float* bv = bias_v + h*HD;
#pragma unroll
        for (int f = 0; f < 2; ++f) {
            const int k0 = f*32 + kd;
            bf16x8 q1 = *(const bf16x8*)(qp  + k0);
            bf16x8 q2 = *(const bf16x8*)(qp2 + k0);
#pragma unroll
            for (int j = 0; j < 8; ++j) {
                const float fu = bu[k0+j], fv = bv[k0+j];
                aqu [f][j] = (bf16_t)(((float)q1[j] + fu) * 0.125f);
                aqv [f][j] = (bf16_t)(((float)q1[j] + fv) * 0.125f);
                aqv2[f][j] = (bf16_t)(((float)q2[j] + fv) * 0.125f);
            }
        }
    }

    float m_run = -1e30f, l_run = 0.0f;
    f32x4 oacc[4];
    f32x4 zf = {0.f, 0.f, 0.f, 0.f};
#pragma unroll
    for (int nf = 0; nf < 4; ++nf) oacc[nf] = zf;

    // ---- lane-constant LDS read bases (row&7 == lr&7 in all families) ----
    const int lsw = (lr & 7) << 3;
    const bf16_t* KlA = &Kl[lr*64 + (kd ^ lsw)];
    const bf16_t* KlB = &Kl[lr*64 + ((32 + kd) ^ lsw)];
    const bf16_t* VlA = &Vl[lr*64 + (kd ^ lsw)];
    const bf16_t* VlB = &Vl[lr*64 + ((32 + kd) ^ lsw)];
    const int rrow0 = 48 - 16*w + lr;              // rr = rrow0 + 16jf; rr&7 == lr&7
    const bf16_t* R1A = &R1l[rrow0*64 + (kd ^ lsw)];
    const bf16_t* R1B = &R1l[rrow0*64 + ((32 + kd) ^ lsw)];
    const bf16_t* R2A = &R2l[rrow0*64 + (kd ^ lsw)];
    const bf16_t* R2B = &R2l[rrow0*64 + ((32 + kd) ^ lsw)];
    const float*  ppb = &pp[w][lr][4*lkg + 15 - lr];   // + 16j + r
    float*        ppw = &pp[w][lr][4*lkg];             // + 16jf (f32x4)
    bf16_t*       plw = &pl[w][lr][4*lkg];             // + 16j (bf16x4)
    const bf16_t* plr = &pl[w][lr][0];                 // + kd / 32+kd

    // ---- gll source pointers, advanced by constant strides per tile ----
    const int rsh   = lane >> 3;
    const int colSw = ((lane & 7) * 8) ^ (rsh << 3);
    const int kvRow = 16*w + rsh;
    const int rRow  = 32*w + rsh;
    const bf16_t* Kg  = K  + (size_t)(b*T_SEQ)*HID + h*HD + (size_t)kvRow*HID + colSw;
    const bf16_t* Vg  = VT + (size_t)((b*NH + h)*HD)*T_SEQ + (size_t)kvRow*T_SEQ + colSw;
    const bf16_t* Rb  = RK + h*HD;
    const bf16_t* R1g = Rb + (ptrdiff_t)(T_SEQ - 64 - t0 + rRow)*HID + colSw;
    const bf16_t* R2g = Rb + (ptrdiff_t)(-65 - t0 + rRow)*HID + colSw;

    for (int s0 = 0; s0 < T_SEQ; s0 += 64) {
        const bool anyB1 = (s0 <= t0 + 63);
        const bool anyB2 = (s0 >= t0 - 61);

        // ---- STAGE via global_load_lds ----
        __syncthreads();
#pragma unroll
        for (int i = 0; i < 2; ++i) {
            gll16(Kg + (size_t)(8*i)*HID,   &Kl[(2*w + i)*512]);
            gll16(Vg + (size_t)(8*i)*T_SEQ, &Vl[(2*w + i)*512]);
        }
        if (anyB1) {
#pragma unroll
            for (int i = 0; i < 4; ++i)
                gll16(R1g + (size_t)(8*i)*HID, &R1l[(4*w + i)*512]);
        }
        if (anyB2) {
#pragma unroll
            for (int i = 0; i < 4; ++i)
                gll16(R2g + (size_t)(8*i)*HID, &R2l[(4*w + i)*512]);
        }
        __syncthreads();
        Kg  += (size_t)64*HID;
        Vg  += 64;
        R1g += (size_t)64*HID;
        R2g += (size_t)64*HID;

        // ---- content scores: sc[j][r] = S[s=s0+16j+4lkg+r][q=tb+lr]
        f32x4 sc[4];
#pragma unroll
        for (int j = 0; j < 4; ++j)
            sc[j] = mfma16(*(const bf16x8*)(KlB + j*1024), aqu[1],
                     mfma16(*(const bf16x8*)(KlA + j*1024), aqu[0], zf));

        const int dbase = s0 - tb + 4*lkg - lr;    // dt = dbase + 16j + r

        // ---- branch 1 (s<=t)
        if (s0 <= tb + 15) {
#pragma unroll
            for (int jf = 0; jf < 5; ++jf) {
                f32x4 c = mfma16(*(const bf16x8*)(R1B + jf*1024), aqv[1],
                           mfma16(*(const bf16x8*)(R1A + jf*1024), aqv[0], zf));
                *(f32x4*)(ppw + 16*jf) = c;
            }
            if (s0 <= tb - 63) {
#pragma unroll
                for (int j = 0; j < 4; ++j)
#pragma unroll
                    for (int r = 0; r < 4; ++r)
                        sc[j][r] += ppb[16*j + r];
            } else {
#pragma unroll
                for (int j = 0; j < 4; ++j)
#pragma unroll
                    for (int r = 0; r < 4; ++r) {
                        const float v = ppb[16*j + r];
                        sc[j][r] += (dbase + 16*j + r <= 0) ? v : 0.0f;
                    }
            }
        }
        // ---- branch 2 (s>=t+2, query row t+1)
        if (s0 >= tb - 61) {
#pragma unroll
            for (int jf = 0; jf < 5; ++jf) {
                f32x4 c = mfma16(*(const bf16x8*)(R2B + jf*1024), aqv2[1],
                           mfma16(*(const bf16x8*)(R2A + jf*1024), aqv2[0], zf));
                *(f32x4*)(ppw + 16*jf) = c;
            }
            if (s0 >= tb + 17) {
#pragma unroll
                for (int j = 0; j < 4; ++j)
#pragma unroll
                    for (int r = 0; r < 4; ++r)
                        sc[j][r] += ppb[16*j + r];
            } else {
#pragma unroll
                for (int j = 0; j < 4; ++j)
#pragma unroll
                    for (int r = 0; r < 4; ++r) {
                        const float v = ppb[16*j + r];
                        sc[j][r] += (dbase + 16*j + r >= 2) ? v : 0.0f;
                    }
            }
        }

        // ---- online softmax: row in-lane (16 vals) + 2 shfls
        float mx = fmaxf(fmaxf(fmaxf(sc[0][0], sc[0][1]), fmaxf(sc[0][2], sc[0][3])),
                         fmaxf(fmaxf(sc[1][0], sc[1][1]), fmaxf(sc[1][2], sc[1][3])));
        mx = fmaxf(mx, fmaxf(fmaxf(fmaxf(sc[2][0], sc[2][1]), fmaxf(sc[2][2], sc[2][3])),
                             fmaxf(fmaxf(sc[3][0], sc[3][1]), fmaxf(sc[3][2], sc[3][3]))));
        mx = fmaxf(mx, __shfl_xor(mx, 16, 64));
        mx = fmaxf(mx, __shfl_xor(mx, 32, 64));
        const float mnew = fmaxf(m_run, mx);
        const bool resc = !__all(mx <= m_run);     // exact: if false, fac==1
        float fac = 1.0f;
        if (resc) fac = __expf(m_run - mnew);
        m_run = mnew;
        float sum = 0.0f;
#pragma unroll
        for (int j = 0; j < 4; ++j) {
            bf16x4 pk;
#pragma unroll
            for (int r = 0; r < 4; ++r) {
                const float p = __expf(sc[j][r] - mnew);
                sum += p;
                pk[r] = (bf16_t)p;
            }
            *(bf16x4*)(plw + 16*j) = pk;
        }
        sum += __shfl_xor(sum, 16, 64);
        sum += __shfl_xor(sum, 32, 64);
        l_run = l_run * fac + sum;
        if (resc) {
#pragma unroll
            for (int r = 0; r < 4; ++r) {
                const float facq = __shfl(fac, 4*lkg + r, 64);
#pragma unroll
                for (int nf = 0; nf < 4; ++nf) oacc[nf][r] *= facq;
            }
        }

        // ---- PV: O += P @ V
        bf16x8 pa0 = *(const bf16x8*)(plr + kd);
        bf16x8 pa1 = *(const bf16x8*)(plr + 32 + kd);
#pragma unroll
        for (int nf = 0; nf < 4; ++nf)
            oacc[nf] = mfma16(pa1, *(const bf16x8*)(VlB + nf*1024),
                        mfma16(pa0, *(const bf16x8*)(VlA + nf*1024), oacc[nf]));
    }

    // ---- epilogue
    const float linv = 1.0f / l_run;
#pragma unroll
    for (int r = 0; r < 4; ++r) {
        const float lq = __shfl(linv, 4*lkg + r, 64);
        const int t = tb + 4*lkg + r;
#pragma unroll
        for (int nf = 0; nf < 4; ++nf)
            AO[(size_t)(b*T_SEQ + t)*HID + h*HD + nf*16 + lr] = (bf16_t)(oacc[nf][r] * lq);
    }
}

extern "C" void kernel_launch(void* const* d_in, const int* in_sizes, int n_in,
                              void* d_out, int out_size, void* d_ws, size_t ws_size,
                              hipStream_t stream) {
    const float* x    = (const float*)d_in[0];
    const float* pos  = (const float*)d_in[1];
    const float* Wq   = (const float*)d_in[2];
    const float* Wk   = (const float*)d_in[3];
    const float* Wv   = (const float*)d_in[4];
    const float* Wo   = (const float*)d_in[5];
    const float* Wrel = (const float*)d_in[6];
    const float* bu   = (const float*)d_in[7];
    const float* bv   = (const float*)d_in[8];

    // ws layout (bf16 elems, M1 = 1M):
    //  qb 0-4 | kb 4-8 | vtb 8-12 | rkb 12-14 | ab 14-18 (xb aliases ab) |
    //  pb 18-20 | wqb 20-21 | wkb 21-22 | wvb 22-23 | wob 23-24 | wrelb 24-25
    //  = 50 MiB total.
    bf16_t* ws   = (bf16_t*)d_ws;
    const size_t M1 = 1024u * 1024u;
    bf16_t* qb    = ws;
    bf16_t* kb    = ws + 4*M1;
    bf16_t* vtb   = ws + 8*M1;
    bf16_t* rkb   = ws + 12*M1;
    bf16_t* ab    = ws + 14*M1;
    bf16_t* xb    = ab;
    bf16_t* pb    = ws + 18*M1;
    bf16_t* wqb   = ws + 20*M1;
    bf16_t* wkb   = ws + 21*M1;
    bf16_t* wvb   = ws + 22*M1;
    bf16_t* wob   = ws + 23*M1;
    bf16_t* wrelb = ws + 24*M1;

    cvt_all<<<5632, 256, 0, stream>>>(x, pos, Wq, Wk, Wv, Wo, Wrel,
                                      xb, pb, wqb, wkb, wvb, wob, wrelb);

    gemm_proj<<<896, 256, 0, stream>>>(xb, pb, wqb, wkb, wvb, wrelb,
                                       qb, kb, vtb, rkb);

    attn_kernel<<<1024, 256, 0, stream>>>(qb, kb, vtb, rkb, bu, bv, ab);

    gemm_out<<<256, 256, 0, stream>>>(ab, wob, (float*)d_out);
}